// Round 1
// baseline (330.786 us; speedup 1.0000x reference)
//
#include <hip/hip_runtime.h>
#include <hip/hip_bf16.h>

typedef unsigned short u16;
typedef unsigned int u32;
typedef __attribute__((ext_vector_type(8))) __bf16 bf16x8;
typedef __attribute__((ext_vector_type(4))) float f32x4;

// Problem constants
constexpr int Bz = 2, Sq = 2048, Dm = 1024, Hn = 16, DK = 64;

__device__ __forceinline__ u16 f2bf(float f) {
    u32 u = __builtin_bit_cast(u32, f);
    return (u16)((u + 0x7FFFu + ((u >> 16) & 1u)) >> 16);   // RNE
}

__device__ __forceinline__ bf16x8 lds_frag(const u16* p) {
    return __builtin_bit_cast(bf16x8, *(const uint4*)p);
}

// ---------------------------------------------------------------------------
// Kernel 1: transpose + cast the 4 weight matrices [K=1024, N=1024] fp32
//           -> Wt [N,K] bf16 (so GEMM B-tiles are contiguous along K)
// ---------------------------------------------------------------------------
__global__ __launch_bounds__(256) void mha_transpose_w(
    const float* __restrict__ w0, const float* __restrict__ w1,
    const float* __restrict__ w2, const float* __restrict__ w3,
    u16* __restrict__ dst_base)
{
    __shared__ float tile[32][33];
    const int z = blockIdx.z;
    const float* src = (z == 0) ? w0 : (z == 1) ? w1 : (z == 2) ? w2 : w3;
    u16* d = dst_base + (size_t)z * Dm * Dm;
    const int bx = blockIdx.x * 32;   // n base
    const int by = blockIdx.y * 32;   // k base
    const int tx = threadIdx.x, ty = threadIdx.y;   // 32 x 8
#pragma unroll
    for (int i = 0; i < 4; i++) {
        int kk = ty + i * 8;
        tile[kk][tx] = src[(size_t)(by + kk) * Dm + bx + tx];
    }
    __syncthreads();
#pragma unroll
    for (int i = 0; i < 4; i++) {
        int nn = ty + i * 8;
        d[(size_t)(bx + nn) * Dm + by + tx] = f2bf(tile[tx][nn]);
    }
}

// ---------------------------------------------------------------------------
// Shared GEMM core: C[128x128] = A[128xK] @ Wt[128xK]^T, K=1024, BK=32
// 256 threads = 4 waves (2x2), each wave 64x64 via 4x4 mfma_f32_16x16x32_bf16
// LDS row stride 40 elems (80B): 16B-aligned, 2-way bank aliasing only (free)
// ---------------------------------------------------------------------------
template<bool AF32>
__device__ __forceinline__ void gemm_core_128(
    const void* __restrict__ Abase, const u16* __restrict__ Bbase,
    u16* As, u16* Bs, f32x4 (&acc)[4][4])
{
    constexpr int K = 1024;
    const int tid  = threadIdx.x;
    const int lane = tid & 63;
    const int wm = (tid >> 7) & 1, wn = (tid >> 6) & 1;
    const int frow = lane & 15, quad = lane >> 4;
    const int srow = tid >> 1;            // 0..127
    const int scol = (tid & 1) << 4;      // 0 or 16

#pragma unroll
    for (int mi = 0; mi < 4; mi++)
#pragma unroll
        for (int ni = 0; ni < 4; ni++) acc[mi][ni] = (f32x4){0.f, 0.f, 0.f, 0.f};

    for (int k0 = 0; k0 < K; k0 += 32) {
        // ---- stage A tile (128x32) ----
        if constexpr (AF32) {
            const float* ap = (const float*)Abase + (size_t)srow * K + k0 + scol;
            float4 v0 = *(const float4*)(ap + 0),  v1 = *(const float4*)(ap + 4);
            float4 v2 = *(const float4*)(ap + 8),  v3 = *(const float4*)(ap + 12);
            u32 p0 = f2bf(v0.x) | ((u32)f2bf(v0.y) << 16);
            u32 p1 = f2bf(v0.z) | ((u32)f2bf(v0.w) << 16);
            u32 p2 = f2bf(v1.x) | ((u32)f2bf(v1.y) << 16);
            u32 p3 = f2bf(v1.z) | ((u32)f2bf(v1.w) << 16);
            u32 p4 = f2bf(v2.x) | ((u32)f2bf(v2.y) << 16);
            u32 p5 = f2bf(v2.z) | ((u32)f2bf(v2.w) << 16);
            u32 p6 = f2bf(v3.x) | ((u32)f2bf(v3.y) << 16);
            u32 p7 = f2bf(v3.z) | ((u32)f2bf(v3.w) << 16);
            *(uint4*)&As[srow * 40 + scol]     = make_uint4(p0, p1, p2, p3);
            *(uint4*)&As[srow * 40 + scol + 8] = make_uint4(p4, p5, p6, p7);
        } else {
            const uint4* ap = (const uint4*)((const u16*)Abase + (size_t)srow * K + k0 + scol);
            uint4 u0 = ap[0], u1 = ap[1];
            *(uint4*)&As[srow * 40 + scol]     = u0;
            *(uint4*)&As[srow * 40 + scol + 8] = u1;
        }
        // ---- stage B tile (128x32) from Wt [N,K] ----
        {
            const uint4* bp = (const uint4*)(Bbase + (size_t)srow * K + k0 + scol);
            uint4 u0 = bp[0], u1 = bp[1];
            *(uint4*)&Bs[srow * 40 + scol]     = u0;
            *(uint4*)&Bs[srow * 40 + scol + 8] = u1;
        }
        __syncthreads();
        bf16x8 af[4], bfr[4];
#pragma unroll
        for (int mi = 0; mi < 4; mi++)
            af[mi] = lds_frag(&As[(wm * 64 + mi * 16 + frow) * 40 + quad * 8]);
#pragma unroll
        for (int ni = 0; ni < 4; ni++)
            bfr[ni] = lds_frag(&Bs[(wn * 64 + ni * 16 + frow) * 40 + quad * 8]);
#pragma unroll
        for (int mi = 0; mi < 4; mi++)
#pragma unroll
            for (int ni = 0; ni < 4; ni++)
                acc[mi][ni] = __builtin_amdgcn_mfma_f32_16x16x32_bf16(
                    af[mi], bfr[ni], acc[mi][ni], 0, 0, 0);
        __syncthreads();
    }
}

// ---------------------------------------------------------------------------
// Kernel 2: QKV projections. z=0: Q'-> [B,H,S,DK]; z=1: K'-> [B,H,S,DK];
//           z=2: V'-> TRANSPOSED [B,H,DK,S] (for contiguous-key PV staging)
// ---------------------------------------------------------------------------
__global__ __launch_bounds__(256) void mha_proj_qkv(
    const float* __restrict__ qin, const float* __restrict__ kin, const float* __restrict__ vin,
    const u16* __restrict__ Wqt, const u16* __restrict__ Wkt, const u16* __restrict__ Wvt,
    const float* __restrict__ bq, const float* __restrict__ bk, const float* __restrict__ bv,
    u16* __restrict__ Qh, u16* __restrict__ Kh, u16* __restrict__ Vt)
{
    __shared__ __align__(16) u16 As[128 * 40];
    __shared__ __align__(16) u16 Bs[128 * 40];
    const int z = blockIdx.z;
    const float* A    = (z == 0) ? qin : (z == 1) ? kin : vin;
    const u16*   Wt   = (z == 0) ? Wqt : (z == 1) ? Wkt : Wvt;
    const float* bias = (z == 0) ? bq  : (z == 1) ? bk  : bv;
    u16*         dst  = (z == 0) ? Qh  : (z == 1) ? Kh  : Vt;
    const int m0 = blockIdx.y * 128, n0 = blockIdx.x * 128;

    f32x4 acc[4][4];
    gemm_core_128<true>(A + (size_t)m0 * Dm, Wt + (size_t)n0 * Dm, As, Bs, acc);

    const int tid = threadIdx.x, lane = tid & 63;
    const int wm = (tid >> 7) & 1, wn = (tid >> 6) & 1;
    const int frow = lane & 15, quad = lane >> 4;
#pragma unroll
    for (int mi = 0; mi < 4; mi++)
#pragma unroll
        for (int ni = 0; ni < 4; ni++)
#pragma unroll
            for (int r = 0; r < 4; r++) {
                int m = m0 + wm * 64 + mi * 16 + quad * 4 + r;   // global row (b*S+s)
                int n = n0 + wn * 64 + ni * 16 + frow;           // global col (h*DK+dk)
                float val = acc[mi][ni][r] + bias[n];
                int b = m >> 11, s = m & (Sq - 1);
                int h = n >> 6, dk = n & (DK - 1);
                size_t idx = (z < 2)
                    ? ((size_t)(b * Hn + h) * Sq + s) * DK + dk    // [B,H,S,DK]
                    : ((size_t)(b * Hn + h) * DK + dk) * Sq + s;   // [B,H,DK,S]
                dst[idx] = f2bf(val);
            }
}

// ---------------------------------------------------------------------------
// Kernel 3: flash attention. Block = (64 q) x (b,h); 64-key tiles, online softmax.
// ---------------------------------------------------------------------------
__global__ __launch_bounds__(256) void mha_attn(
    const u16* __restrict__ Qh, const u16* __restrict__ Kh, const u16* __restrict__ Vt,
    const int* __restrict__ mask, u16* __restrict__ X)
{
    const int b = blockIdx.z, h = blockIdx.y, q0 = blockIdx.x * 64;
    const int tid = threadIdx.x, lane = tid & 63, w = tid >> 6;
    const int frow = lane & 15, quad = lane >> 4;

    __shared__ __align__(16) u16 Qs[64 * 72];
    __shared__ __align__(16) u16 Ks[64 * 72];
    __shared__ __align__(16) u16 Vts[64 * 72];
    __shared__ __align__(16) u16 Ps[4 * 16 * 72];
    __shared__ float msk[64];

    const size_t bh = (size_t)(b * Hn + h);
    const u16* Qp = Qh + bh * Sq * DK;
    const u16* Kp = Kh + bh * Sq * DK;
    const u16* Vp = Vt + bh * DK * Sq;   // [feat][key]

    // stage Q tile (64 x 64)
    {
        int row = tid >> 2, cs = (tid & 3) * 16;
        const uint4* sp = (const uint4*)(Qp + (size_t)(q0 + row) * DK + cs);
        uint4 u0 = sp[0], u1 = sp[1];
        *(uint4*)&Qs[row * 72 + cs]     = u0;
        *(uint4*)&Qs[row * 72 + cs + 8] = u1;
    }

    float m_row[4], l_row[4];
    f32x4 o[4];
#pragma unroll
    for (int r = 0; r < 4; r++) { m_row[r] = -1e30f; l_row[r] = 0.f; }
#pragma unroll
    for (int ni = 0; ni < 4; ni++) o[ni] = (f32x4){0.f, 0.f, 0.f, 0.f};

    for (int k0 = 0; k0 < Sq; k0 += 64) {
        // ---- stage K tile [key][feat], V tile [feat][key], mask bias ----
        {
            int row = tid >> 2, cs = (tid & 3) * 16;
            const uint4* kp = (const uint4*)(Kp + (size_t)(k0 + row) * DK + cs);
            uint4 a0 = kp[0], a1 = kp[1];
            const uint4* vp = (const uint4*)(Vp + (size_t)row * Sq + k0 + cs);
            uint4 b0 = vp[0], b1 = vp[1];
            *(uint4*)&Ks[row * 72 + cs]      = a0;
            *(uint4*)&Ks[row * 72 + cs + 8]  = a1;
            *(uint4*)&Vts[row * 72 + cs]     = b0;
            *(uint4*)&Vts[row * 72 + cs + 8] = b1;
            if (tid < 64) msk[tid] = (mask[b * Sq + k0 + tid] != 0) ? -1e10f : 0.0f;
        }
        __syncthreads();

        // ---- S = Q Kt  (wave w owns q rows [w*16, w*16+16)) ----
        f32x4 s[4];
#pragma unroll
        for (int ni = 0; ni < 4; ni++) s[ni] = (f32x4){0.f, 0.f, 0.f, 0.f};
#pragma unroll
        for (int kc = 0; kc < 2; kc++) {
            bf16x8 a = lds_frag(&Qs[(w * 16 + frow) * 72 + kc * 32 + quad * 8]);
#pragma unroll
            for (int ni = 0; ni < 4; ni++) {
                bf16x8 bb = lds_frag(&Ks[(ni * 16 + frow) * 72 + kc * 32 + quad * 8]);
                s[ni] = __builtin_amdgcn_mfma_f32_16x16x32_bf16(a, bb, s[ni], 0, 0, 0);
            }
        }

        // ---- online softmax (C-layout: row = quad*4+r, col = ni*16+frow) ----
        float sc[4][4];
#pragma unroll
        for (int ni = 0; ni < 4; ni++) {
            float mb = msk[ni * 16 + frow];
#pragma unroll
            for (int r = 0; r < 4; r++) sc[ni][r] = s[ni][r] * 0.125f + mb;
        }
        float mnew[4], alpha[4];
#pragma unroll
        for (int r = 0; r < 4; r++) {
            float v = fmaxf(fmaxf(sc[0][r], sc[1][r]), fmaxf(sc[2][r], sc[3][r]));
#pragma unroll
            for (int off = 1; off < 16; off <<= 1) v = fmaxf(v, __shfl_xor(v, off));
            mnew[r]  = fmaxf(m_row[r], v);
            alpha[r] = __expf(m_row[r] - mnew[r]);
            m_row[r] = mnew[r];
        }
#pragma unroll
        for (int ni = 0; ni < 4; ni++)
#pragma unroll
            for (int r = 0; r < 4; r++) sc[ni][r] = __expf(sc[ni][r] - mnew[r]);
#pragma unroll
        for (int r = 0; r < 4; r++) {
            float rs = sc[0][r] + sc[1][r] + sc[2][r] + sc[3][r];
#pragma unroll
            for (int off = 1; off < 16; off <<= 1) rs += __shfl_xor(rs, off);
            l_row[r] = l_row[r] * alpha[r] + rs;
        }
#pragma unroll
        for (int ni = 0; ni < 4; ni++) {
            o[ni][0] *= alpha[0]; o[ni][1] *= alpha[1];
            o[ni][2] *= alpha[2]; o[ni][3] *= alpha[3];
        }
        // ---- P: C-layout -> A-operand layout via LDS (wave-private region) ----
        u16* Pw = &Ps[w * 16 * 72];
#pragma unroll
        for (int ni = 0; ni < 4; ni++)
#pragma unroll
            for (int r = 0; r < 4; r++)
                Pw[(quad * 4 + r) * 72 + ni * 16 + frow] = f2bf(sc[ni][r]);
        __syncthreads();

        // ---- O += P V ----
#pragma unroll
        for (int kc = 0; kc < 2; kc++) {
            bf16x8 a = lds_frag(&Ps[(w * 16 + frow) * 72 + kc * 32 + quad * 8]);
#pragma unroll
            for (int ni = 0; ni < 4; ni++) {
                bf16x8 bb = lds_frag(&Vts[(ni * 16 + frow) * 72 + kc * 32 + quad * 8]);
                o[ni] = __builtin_amdgcn_mfma_f32_16x16x32_bf16(a, bb, o[ni], 0, 0, 0);
            }
        }
        __syncthreads();
    }

    // ---- epilogue: X[b][s][h*64+feat] = o / l ----
#pragma unroll
    for (int ni = 0; ni < 4; ni++)
#pragma unroll
        for (int r = 0; r < 4; r++) {
            int qg = q0 + w * 16 + quad * 4 + r;
            int feat = ni * 16 + frow;
            X[((size_t)(b * Sq + qg)) * Dm + h * DK + feat] = f2bf(o[ni][r] / l_row[r]);
        }
}

// ---------------------------------------------------------------------------
// Kernel 4: out = X @ Wo + bo  (fp32 output)
// ---------------------------------------------------------------------------
__global__ __launch_bounds__(256) void mha_oproj(
    const u16* __restrict__ X, const u16* __restrict__ Wot,
    const float* __restrict__ bo, float* __restrict__ out)
{
    __shared__ __align__(16) u16 As[128 * 40];
    __shared__ __align__(16) u16 Bs[128 * 40];
    const int m0 = blockIdx.y * 128, n0 = blockIdx.x * 128;
    f32x4 acc[4][4];
    gemm_core_128<false>(X + (size_t)m0 * Dm, Wot + (size_t)n0 * Dm, As, Bs, acc);
    const int tid = threadIdx.x, lane = tid & 63;
    const int wm = (tid >> 7) & 1, wn = (tid >> 6) & 1;
    const int frow = lane & 15, quad = lane >> 4;
#pragma unroll
    for (int mi = 0; mi < 4; mi++)
#pragma unroll
        for (int ni = 0; ni < 4; ni++)
#pragma unroll
            for (int r = 0; r < 4; r++) {
                int m = m0 + wm * 64 + mi * 16 + quad * 4 + r;
                int n = n0 + wn * 64 + ni * 16 + frow;
                out[(size_t)m * Dm + n] = acc[mi][ni][r] + bo[n];
            }
}

// ---------------------------------------------------------------------------
extern "C" void kernel_launch(void* const* d_in, const int* in_sizes, int n_in,
                              void* d_out, int out_size, void* d_ws, size_t ws_size,
                              hipStream_t stream)
{
    const float* qin  = (const float*)d_in[0];
    const float* kin  = (const float*)d_in[1];
    const float* vin  = (const float*)d_in[2];
    const int*   mask = (const int*)d_in[3];
    const float* Wq   = (const float*)d_in[4];
    const float* bq   = (const float*)d_in[5];
    const float* Wk   = (const float*)d_in[6];
    const float* bk   = (const float*)d_in[7];
    const float* Wv   = (const float*)d_in[8];
    const float* bv   = (const float*)d_in[9];
    const float* Wo   = (const float*)d_in[10];
    const float* bo   = (const float*)d_in[11];
    float* out = (float*)d_out;

    u16* ws = (u16*)d_ws;
    const size_t MW = (size_t)Dm * Dm;            // 1M elems per weight
    const size_t MT = (size_t)Bz * Hn * Sq * DK;  // 4M elems per tensor
    u16* Wqt = ws;
    u16* Wkt = ws + MW;
    u16* Wvt = ws + 2 * MW;
    u16* Wot = ws + 3 * MW;
    u16* Qh  = ws + 4 * MW;
    u16* Kh  = Qh + MT;
    u16* Vt  = Kh + MT;
    u16* X   = Vt + MT;   // total ~42 MB of workspace

    hipLaunchKernelGGL(mha_transpose_w, dim3(32, 32, 4), dim3(32, 8), 0, stream,
                       Wq, Wk, Wv, Wo, Wqt);
    hipLaunchKernelGGL(mha_proj_qkv, dim3(8, 32, 3), dim3(256), 0, stream,
                       qin, kin, vin, Wqt, Wkt, Wvt, bq, bk, bv, Qh, Kh, Vt);
    hipLaunchKernelGGL(mha_attn, dim3(32, 16, 2), dim3(256), 0, stream,
                       Qh, Kh, Vt, mask, X);
    hipLaunchKernelGGL(mha_oproj, dim3(8, 32), dim3(256), 0, stream,
                       X, Wot, bo, out);
}

// Round 2
// 261.579 us; speedup vs baseline: 1.2646x; 1.2646x over previous
//
#include <hip/hip_runtime.h>
#include <hip/hip_bf16.h>

typedef unsigned short u16;
typedef unsigned int u32;
typedef __attribute__((ext_vector_type(8))) __bf16 bf16x8;
typedef __attribute__((ext_vector_type(4))) float f32x4;
typedef __attribute__((ext_vector_type(16))) float f32x16;

constexpr int Bz = 2, Sq = 2048, Dm = 1024, Hn = 16, DK = 64;

__device__ __forceinline__ u16 f2bf(float f) {
    u32 u = __builtin_bit_cast(u32, f);
    return (u16)((u + 0x7FFFu + ((u >> 16) & 1u)) >> 16);   // RNE
}

__device__ __forceinline__ u32 pack_bf16(float a, float b) {
#if __has_builtin(__builtin_amdgcn_cvt_pk_bf16_f32)
    return __builtin_bit_cast(u32, __builtin_amdgcn_cvt_pk_bf16_f32(a, b));
#else
    return (u32)f2bf(a) | ((u32)f2bf(b) << 16);
#endif
}

__device__ __forceinline__ bf16x8 lds_frag(const u16* p) {
    return __builtin_bit_cast(bf16x8, *(const uint4*)p);
}

// async global->LDS, 16B per lane; LDS dest = wave-uniform base + lane*16
__device__ __forceinline__ void gll16(const u16* g, u16* l) {
    __builtin_amdgcn_global_load_lds(
        (const __attribute__((address_space(1))) void*)g,
        (__attribute__((address_space(3))) void*)l, 16, 0, 0);
}

// ---------------------------------------------------------------------------
// Kernel 0: cast q,k,v fp32 -> bf16 [4096,1024]
// ---------------------------------------------------------------------------
__global__ __launch_bounds__(256) void mha_cast(
    const float* __restrict__ q, const float* __restrict__ k,
    const float* __restrict__ v, u16* __restrict__ dst_base)
{
    const int z = blockIdx.z;
    const float* s = (z == 0) ? q : (z == 1) ? k : v;
    u16* d = dst_base + (size_t)z * 4 * 1024 * 1024;
    size_t i = ((size_t)blockIdx.x * 256 + threadIdx.x) * 8;
    float4 a = *(const float4*)(s + i);
    float4 b = *(const float4*)(s + i + 4);
    *(uint4*)(d + i) = make_uint4(pack_bf16(a.x, a.y), pack_bf16(a.z, a.w),
                                  pack_bf16(b.x, b.y), pack_bf16(b.z, b.w));
}

// ---------------------------------------------------------------------------
// Kernel 1: transpose + cast the 4 weight matrices -> Wt [N,K] bf16
// ---------------------------------------------------------------------------
__global__ __launch_bounds__(256) void mha_transpose_w(
    const float* __restrict__ w0, const float* __restrict__ w1,
    const float* __restrict__ w2, const float* __restrict__ w3,
    u16* __restrict__ dst_base)
{
    __shared__ float tile[32][33];
    const int z = blockIdx.z;
    const float* src = (z == 0) ? w0 : (z == 1) ? w1 : (z == 2) ? w2 : w3;
    u16* d = dst_base + (size_t)z * Dm * Dm;
    const int bx = blockIdx.x * 32, by = blockIdx.y * 32;
    const int tx = threadIdx.x, ty = threadIdx.y;   // 32 x 8
#pragma unroll
    for (int i = 0; i < 4; i++) {
        int kk = ty + i * 8;
        tile[kk][tx] = src[(size_t)(by + kk) * Dm + bx + tx];
    }
    __syncthreads();
#pragma unroll
    for (int i = 0; i < 4; i++) {
        int nn = ty + i * 8;
        d[(size_t)(bx + nn) * Dm + by + tx] = f2bf(tile[tx][nn]);
    }
}

// ---------------------------------------------------------------------------
// m97-style GEMM core: C[128x128] = A[128xK] @ B[128xK]^T, K=1024, BK=32,
// bf16 A/B, global_load_lds staging into unpadded [128][32] LDS tiles.
// ---------------------------------------------------------------------------
__device__ __forceinline__ void gemm_core_dma(
    const u16* __restrict__ Ab, const u16* __restrict__ Bb,
    u16* As, u16* Bs, f32x4 (&acc)[4][4])
{
    const int tid = threadIdx.x, lane = tid & 63;
    const int wm = (tid >> 7) & 1, wn = (tid >> 6) & 1;
    const int frow = lane & 15, quad = lane >> 4;
    const int r0 = tid >> 2,        c0 = tid & 3;          // id0 = tid
    const int r1 = (tid + 256) >> 2, c1 = tid & 3;         // id1 = tid+256

#pragma unroll
    for (int mi = 0; mi < 4; mi++)
#pragma unroll
        for (int ni = 0; ni < 4; ni++) acc[mi][ni] = (f32x4){0.f, 0.f, 0.f, 0.f};

    for (int k0 = 0; k0 < 1024; k0 += 32) {
        gll16(Ab + (size_t)r0 * 1024 + k0 + c0 * 8, &As[tid * 8]);
        gll16(Ab + (size_t)r1 * 1024 + k0 + c1 * 8, &As[(tid + 256) * 8]);
        gll16(Bb + (size_t)r0 * 1024 + k0 + c0 * 8, &Bs[tid * 8]);
        gll16(Bb + (size_t)r1 * 1024 + k0 + c1 * 8, &Bs[(tid + 256) * 8]);
        __syncthreads();
        bf16x8 af[4], bfr[4];
#pragma unroll
        for (int mi = 0; mi < 4; mi++)
            af[mi] = lds_frag(&As[(wm * 64 + mi * 16 + frow) * 32 + quad * 8]);
#pragma unroll
        for (int ni = 0; ni < 4; ni++)
            bfr[ni] = lds_frag(&Bs[(wn * 64 + ni * 16 + frow) * 32 + quad * 8]);
#pragma unroll
        for (int mi = 0; mi < 4; mi++)
#pragma unroll
            for (int ni = 0; ni < 4; ni++)
                acc[mi][ni] = __builtin_amdgcn_mfma_f32_16x16x32_bf16(
                    af[mi], bfr[ni], acc[mi][ni], 0, 0, 0);
        __syncthreads();
    }
}

// ---------------------------------------------------------------------------
// Kernel 2: QKV projections (A already bf16). z=0: Q->[B,H,S,DK];
//           z=1: K->[B,H,S,DK]; z=2: V-> transposed [B,H,DK,S]
// ---------------------------------------------------------------------------
__global__ __launch_bounds__(256) void mha_proj_qkv(
    const u16* __restrict__ Qb, const u16* __restrict__ Kb, const u16* __restrict__ Vb,
    const u16* __restrict__ Wqt, const u16* __restrict__ Wkt, const u16* __restrict__ Wvt,
    const float* __restrict__ bq, const float* __restrict__ bk, const float* __restrict__ bv,
    u16* __restrict__ Qh, u16* __restrict__ Kh, u16* __restrict__ Vt)
{
    __shared__ __align__(16) u16 As[128 * 32];
    __shared__ __align__(16) u16 Bs[128 * 32];
    const int z = blockIdx.z;
    const u16*   A    = (z == 0) ? Qb : (z == 1) ? Kb : Vb;
    const u16*   Wt   = (z == 0) ? Wqt : (z == 1) ? Wkt : Wvt;
    const float* bias = (z == 0) ? bq  : (z == 1) ? bk  : bv;
    u16*         dst  = (z == 0) ? Qh  : (z == 1) ? Kh  : Vt;
    const int m0 = blockIdx.y * 128, n0 = blockIdx.x * 128;

    f32x4 acc[4][4];
    gemm_core_dma(A + (size_t)m0 * Dm, Wt + (size_t)n0 * Dm, As, Bs, acc);

    const int tid = threadIdx.x, lane = tid & 63;
    const int wm = (tid >> 7) & 1, wn = (tid >> 6) & 1;
    const int frow = lane & 15, quad = lane >> 4;
#pragma unroll
    for (int mi = 0; mi < 4; mi++)
#pragma unroll
        for (int ni = 0; ni < 4; ni++)
#pragma unroll
            for (int r = 0; r < 4; r++) {
                int m = m0 + wm * 64 + mi * 16 + quad * 4 + r;   // b*S+s
                int n = n0 + wn * 64 + ni * 16 + frow;           // h*DK+dk
                float val = acc[mi][ni][r] + bias[n];
                int b = m >> 11, s = m & (Sq - 1);
                int h = n >> 6, dk = n & (DK - 1);
                size_t idx = (z < 2)
                    ? ((size_t)(b * Hn + h) * Sq + s) * DK + dk
                    : ((size_t)(b * Hn + h) * DK + dk) * Sq + s;
                dst[idx] = f2bf(val);
            }
}

// ---------------------------------------------------------------------------
// Kernel 3: flash attention, S^T / O^T formulation with 32x32x16 MFMA.
// Block: 128 q rows (4 waves x 32 q), 64-key tiles.
// Lane roles: qc = lane&31 (q column / m-row), half = lane>>5.
// ---------------------------------------------------------------------------
__global__ __launch_bounds__(256) void mha_attn(
    const u16* __restrict__ Qh, const u16* __restrict__ Kh, const u16* __restrict__ Vt,
    const int* __restrict__ mask, u16* __restrict__ X)
{
    const int b = blockIdx.z, hh = blockIdx.y, q0 = blockIdx.x * 128;
    const int tid = threadIdx.x, lane = tid & 63, w = tid >> 6;
    const int qc = lane & 31, half = lane >> 5;
    constexpr float C2 = 0.125f * 1.44269504f;   // 1/sqrt(DK) * log2(e)

    __shared__ __align__(16) u16 Qs[128 * 64];
    __shared__ __align__(16) u16 Ks[64 * 64];
    __shared__ __align__(16) u16 Vts[64 * 64];
    __shared__ __align__(16) u16 Pls[4 * 32 * 72];
    __shared__ __align__(16) float mskp[64];

    const size_t bh = (size_t)(b * Hn + hh);
    const u16* Qp = Qh + bh * Sq * DK;
    const u16* Kp = Kh + bh * Sq * DK;
    const u16* Vp = Vt + bh * DK * Sq;   // [d][key]
    u16* Pw = &Pls[w * 32 * 72];

    // stage Q tile [128][64] with chunk swizzle c ^= row&7 (rows span all 32 banks)
#pragma unroll
    for (int i = 0; i < 4; i++) {
        int id = tid + i * 256, row = id >> 3, cl = id & 7;
        int cg = cl ^ (row & 7);
        gll16(Qp + (size_t)(q0 + row) * DK + cg * 8, &Qs[id * 8]);
    }
    __syncthreads();
    bf16x8 qf[4];
    {
        int row = w * 32 + qc;
#pragma unroll
        for (int kc = 0; kc < 4; kc++)
            qf[kc] = lds_frag(&Qs[row * 64 + (((kc * 2 + half) ^ (row & 7)) * 8)]);
    }

    float m_l = -3e38f, l_l = 0.f;
    f32x16 o0, o1;
#pragma unroll
    for (int i = 0; i < 16; i++) { o0[i] = 0.f; o1[i] = 0.f; }

    for (int k0 = 0; k0 < Sq; k0 += 64) {
        // ---- stage K [key][dk], Vt [d][key], mask bias (permuted to C-row order) ----
#pragma unroll
        for (int i = 0; i < 2; i++) {
            int id = tid + i * 256, row = id >> 3, cl = id & 7;
            int cg = cl ^ (row & 7);
            gll16(Kp + (size_t)(k0 + row) * DK + cg * 8, &Ks[id * 8]);
            gll16(Vp + (size_t)row * Sq + k0 + cg * 8, &Vts[id * 8]);
        }
        if (tid < 64) {
            int s_ = tid >> 5, h_ = (tid >> 4) & 1, g = (tid >> 2) & 3, r = tid & 3;
            int key = s_ * 32 + 8 * g + 4 * h_ + r;
            mskp[tid] = (mask[b * Sq + k0 + key] != 0) ? -1.44269504e10f : 0.f;
        }
        __syncthreads();

        // ---- S^T = K Q^T : A = K rows (m=key), B = Q rows (n=q) ----
        f32x16 sT0, sT1;
#pragma unroll
        for (int i = 0; i < 16; i++) { sT0[i] = 0.f; sT1[i] = 0.f; }
#pragma unroll
        for (int kc = 0; kc < 4; kc++) {
            const int cs = ((kc * 2 + half) ^ (qc & 7)) * 8;
            bf16x8 ka0 = lds_frag(&Ks[qc * 64 + cs]);
            bf16x8 ka1 = lds_frag(&Ks[(32 + qc) * 64 + cs]);
            sT0 = __builtin_amdgcn_mfma_f32_32x32x16_bf16(ka0, qf[kc], sT0, 0, 0, 0);
            sT1 = __builtin_amdgcn_mfma_f32_32x32x16_bf16(ka1, qf[kc], sT1, 0, 0, 0);
        }

        // ---- online softmax in exp2 domain; per-lane q = w*32+qc ----
        // C row (key_local) = (reg&3) + 8*(reg>>2) + 4*half
        float t0[16], t1[16];
#pragma unroll
        for (int g = 0; g < 4; g++) {
            float4 mb0 = *(const float4*)&mskp[half * 16 + g * 4];
            float4 mb1 = *(const float4*)&mskp[32 + half * 16 + g * 4];
            t0[g * 4 + 0] = fmaf(sT0[g * 4 + 0], C2, mb0.x);
            t0[g * 4 + 1] = fmaf(sT0[g * 4 + 1], C2, mb0.y);
            t0[g * 4 + 2] = fmaf(sT0[g * 4 + 2], C2, mb0.z);
            t0[g * 4 + 3] = fmaf(sT0[g * 4 + 3], C2, mb0.w);
            t1[g * 4 + 0] = fmaf(sT1[g * 4 + 0], C2, mb1.x);
            t1[g * 4 + 1] = fmaf(sT1[g * 4 + 1], C2, mb1.y);
            t1[g * 4 + 2] = fmaf(sT1[g * 4 + 2], C2, mb1.z);
            t1[g * 4 + 3] = fmaf(sT1[g * 4 + 3], C2, mb1.w);
        }
        float vmax = t0[0];
#pragma unroll
        for (int i = 1; i < 16; i++) vmax = fmaxf(vmax, t0[i]);
#pragma unroll
        for (int i = 0; i < 16; i++) vmax = fmaxf(vmax, t1[i]);
        vmax = fmaxf(vmax, __shfl_xor(vmax, 32));
        float mnew = fmaxf(m_l, vmax);
        float alpha = __builtin_amdgcn_exp2f(m_l - mnew);
        m_l = mnew;
        float rs = 0.f;
#pragma unroll
        for (int i = 0; i < 16; i++) { t0[i] = __builtin_amdgcn_exp2f(t0[i] - mnew); rs += t0[i]; }
#pragma unroll
        for (int i = 0; i < 16; i++) { t1[i] = __builtin_amdgcn_exp2f(t1[i] - mnew); rs += t1[i]; }
        rs += __shfl_xor(rs, 32);
        l_l = l_l * alpha + rs;
#pragma unroll
        for (int i = 0; i < 16; i++) { o0[i] *= alpha; o1[i] *= alpha; }

        // ---- P^T -> wave-private LDS [q][key], vectorized b64 writes ----
#pragma unroll
        for (int g = 0; g < 4; g++) {
            *(uint2*)&Pw[qc * 72 + 8 * g + 4 * half] =
                make_uint2(pack_bf16(t0[g * 4 + 0], t0[g * 4 + 1]),
                           pack_bf16(t0[g * 4 + 2], t0[g * 4 + 3]));
            *(uint2*)&Pw[qc * 72 + 32 + 8 * g + 4 * half] =
                make_uint2(pack_bf16(t1[g * 4 + 0], t1[g * 4 + 1]),
                           pack_bf16(t1[g * 4 + 2], t1[g * 4 + 3]));
        }

        // ---- O^T += Vt P^T : A = Vt rows (m=d), B = P rows (n=q) ----
#pragma unroll
        for (int kc = 0; kc < 4; kc++) {
            bf16x8 pf = lds_frag(&Pw[qc * 72 + kc * 16 + half * 8]);
            const int cs = ((kc * 2 + half) ^ (qc & 7)) * 8;
            bf16x8 va0 = lds_frag(&Vts[qc * 64 + cs]);
            bf16x8 va1 = lds_frag(&Vts[(32 + qc) * 64 + cs]);
            o0 = __builtin_amdgcn_mfma_f32_32x32x16_bf16(va0, pf, o0, 0, 0, 0);
            o1 = __builtin_amdgcn_mfma_f32_32x32x16_bf16(va1, pf, o1, 0, 0, 0);
        }
        __syncthreads();
    }

    // ---- epilogue: X[b*S+q][hh*64 + d] bf16; d = dt*32 + 8g + 4*half + r ----
    const float inv = 1.0f / l_l;
    const int qg = q0 + w * 32 + qc;
    u16* Xp = X + (size_t)(b * Sq + qg) * Dm + hh * DK;
#pragma unroll
    for (int g = 0; g < 4; g++) {
        *(uint2*)&Xp[8 * g + 4 * half] =
            make_uint2(pack_bf16(o0[g * 4 + 0] * inv, o0[g * 4 + 1] * inv),
                       pack_bf16(o0[g * 4 + 2] * inv, o0[g * 4 + 3] * inv));
        *(uint2*)&Xp[32 + 8 * g + 4 * half] =
            make_uint2(pack_bf16(o1[g * 4 + 0] * inv, o1[g * 4 + 1] * inv),
                       pack_bf16(o1[g * 4 + 2] * inv, o1[g * 4 + 3] * inv));
    }
}

// ---------------------------------------------------------------------------
// Kernel 4: out = X @ Wo + bo (fp32 output)
// ---------------------------------------------------------------------------
__global__ __launch_bounds__(256) void mha_oproj(
    const u16* __restrict__ X, const u16* __restrict__ Wot,
    const float* __restrict__ bo, float* __restrict__ out)
{
    __shared__ __align__(16) u16 As[128 * 32];
    __shared__ __align__(16) u16 Bs[128 * 32];
    const int m0 = blockIdx.y * 128, n0 = blockIdx.x * 128;
    f32x4 acc[4][4];
    gemm_core_dma(X + (size_t)m0 * Dm, Wot + (size_t)n0 * Dm, As, Bs, acc);
    const int tid = threadIdx.x, lane = tid & 63;
    const int wm = (tid >> 7) & 1, wn = (tid >> 6) & 1;
    const int frow = lane & 15, quad = lane >> 4;
#pragma unroll
    for (int mi = 0; mi < 4; mi++)
#pragma unroll
        for (int ni = 0; ni < 4; ni++)
#pragma unroll
            for (int r = 0; r < 4; r++) {
                int m = m0 + wm * 64 + mi * 16 + quad * 4 + r;
                int n = n0 + wn * 64 + ni * 16 + frow;
                out[(size_t)m * Dm + n] = acc[mi][ni][r] + bo[n];
            }
}

// ---------------------------------------------------------------------------
extern "C" void kernel_launch(void* const* d_in, const int* in_sizes, int n_in,
                              void* d_out, int out_size, void* d_ws, size_t ws_size,
                              hipStream_t stream)
{
    const float* qin  = (const float*)d_in[0];
    const float* kin  = (const float*)d_in[1];
    const float* vin  = (const float*)d_in[2];
    const int*   mask = (const int*)d_in[3];
    const float* Wq   = (const float*)d_in[4];
    const float* bq   = (const float*)d_in[5];
    const float* Wk   = (const float*)d_in[6];
    const float* bk   = (const float*)d_in[7];
    const float* Wv   = (const float*)d_in[8];
    const float* bv   = (const float*)d_in[9];
    const float* Wo   = (const float*)d_in[10];
    const float* bo   = (const float*)d_in[11];
    float* out = (float*)d_out;

    u16* ws = (u16*)d_ws;
    const size_t MW = (size_t)Dm * Dm;            // 1M elems
    const size_t MT = (size_t)Bz * Sq * Dm;       // 4M elems
    u16* Wqt = ws;
    u16* Wkt = ws + MW;
    u16* Wvt = ws + 2 * MW;
    u16* Wot = ws + 3 * MW;
    u16* Qb  = ws + 4 * MW;        // bf16 casts of q,k,v
    u16* Kb  = Qb + MT;
    u16* Vb  = Kb + MT;
    u16* Qh  = Vb + MT;            // head-split projections
    u16* Kh  = Qh + MT;
    u16* Vt  = Kh + MT;
    u16* X   = Qb;                 // alias: Qb dead after proj  (total 56 MB)

    hipLaunchKernelGGL(mha_cast, dim3(2048, 1, 3), dim3(256), 0, stream,
                       qin, kin, vin, Qb);
    hipLaunchKernelGGL(mha_transpose_w, dim3(32, 32, 4), dim3(32, 8), 0, stream,
                       Wq, Wk, Wv, Wo, Wqt);
    hipLaunchKernelGGL(mha_proj_qkv, dim3(8, 32, 3), dim3(256), 0, stream,
                       Qb, Kb, Vb, Wqt, Wkt, Wvt, bq, bk, bv, Qh, Kh, Vt);
    hipLaunchKernelGGL(mha_attn, dim3(16, 16, 2), dim3(256), 0, stream,
                       Qh, Kh, Vt, mask, X);
    hipLaunchKernelGGL(mha_oproj, dim3(8, 32), dim3(256), 0, stream,
                       X, Wot, bo, out);
}